// Round 11
// baseline (275.333 us; speedup 1.0000x reference)
//
#include <hip/hip_runtime.h>
#include <cstdint>
#include <cstddef>

#define BN_EPS 1e-5f
#define BATCH 8192

typedef unsigned long long u64;
typedef uint32_t u32;
typedef int v4i __attribute__((ext_vector_type(4)));
typedef int v16i __attribute__((ext_vector_type(16)));

// float <-> total-order key (ascending with float order on finites)
__device__ __forceinline__ u32 f2k(float f) {
    u32 u = __float_as_uint(f);
    return (u >> 31) ? ~u : (u | 0x80000000u);
}
__device__ __forceinline__ float k2f(u32 k) {
    u32 u = (k & 0x80000000u) ? (k ^ 0x80000000u) : ~k;
    return __uint_as_float(u);
}
// exact fp32 BN chain — bit-identical to the reference epilogue semantics
__device__ __forceinline__ float bn_eval(float conv, float B, float iv, float sh) {
    return __fadd_rn(__fmul_rn(__fadd_rn(conv, B), iv), sh);
}

// ---------------- one merged prep kernel (R8-verified) ----------------
__global__ __launch_bounds__(256) void prep_all(
    const float* w1, const float* b1, const float* w2, const float* b2,
    const float* w3, const float* b3, const float* w4, const float* b4,
    const float* wf,
    const float* g1, const float* be1, const float* m1, const float* v1,
    const float* g2, const float* be2, const float* m2, const float* v2,
    const float* g3, const float* be3, const float* m3, const float* v3,
    const float* g4, const float* be4, const float* m4, const float* v4,
    float* s1f, float* T1, u32* wt2w, int* T2,
    uint4* b3i8, int* C3, u64* wt4, int* T4, u64* wtf) {
    int t = blockIdx.x * 256 + threadIdx.x;

    if (t < 384) {
        int co = t / 12, k = t % 12;
        float val = 0.f;
        if (k < 9) {
            float iv = g1[co] * rsqrtf(v1[co] + BN_EPS);
            float d = (iv < 0.f) ? -1.f : 1.f;
            val = ((w1[co * 9 + k] >= 0.f) ? 1.f : -1.f) * d;
        }
        s1f[t] = val;
    } else if (t < 416) {
        int co = t - 384;
        float iv = g1[co] * rsqrtf(v1[co] + BN_EPS);
        float sh = be1[co] - m1[co] * iv;
        float B = b1[co];
        bool flip = (iv < 0.f);
        auto pred = [&](float sp) {
            float sum = flip ? -sp : sp;
            return bn_eval(sum, B, iv, sh) >= 0.f;
        };
        u32 lo = f2k(-3.0e38f), hi = f2k(3.0e38f);
        float Tv;
        if (pred(k2f(lo))) Tv = k2f(lo);
        else if (!pred(k2f(hi))) Tv = __uint_as_float(0x7F800000u);
        else {
            while (hi - lo > 1u) {
                u32 mid = lo + ((hi - lo) >> 1);
                if (pred(k2f(mid))) hi = mid; else lo = mid;
            }
            Tv = k2f(hi);
        }
        T1[co] = Tv;
    } else if (t < 608) {
        int idx = t - 416;
        int co = idx / 3, kw = idx % 3;
        float iv = g2[co] * rsqrtf(v2[co] + BN_EPS);
        bool flip = (iv < 0.f);
        u32 wb = 0;
        for (int ci = 0; ci < 32; ++ci)
            wb |= (u32)((w2[(co * 32 + ci) * 3 + kw] >= 0.f) != flip) << ci;
        wt2w[co * 4 + kw] = wb;
    } else if (t < 800) {
        int idx = t - 608;
        int co = idx & 63, cls = idx >> 6;
        float iv = g2[co] * rsqrtf(v2[co] + BN_EPS);
        float sh = be2[co] - m2[co] * iv;
        float B = b2[co];
        bool flip = (iv < 0.f);
        int spur = 0, nv = 3;
        if (cls == 1) { nv = 2; for (int ci = 0; ci < 32; ++ci) spur += (int)((w2[(co * 32 + ci) * 3 + 0] >= 0.f) != flip); }
        if (cls == 2) { nv = 2; for (int ci = 0; ci < 32; ++ci) spur += (int)((w2[(co * 32 + ci) * 3 + 2] >= 0.f) != flip); }
        int maxp = 32 * nv + spur;
        int T = -1;
        for (int p = 0; p <= maxp; ++p) {
            int conv = flip ? (2 * (p - spur) - 32 * nv) : (32 * nv - 2 * (p - spur));
            float y = bn_eval((float)conv, B, iv, sh);
            if ((y >= 0.f) && (T == p - 1)) T = p;
        }
        T2[cls * 64 + co] = T;
    } else if (t < 2336) {
        int idx = t - 800;
        int q = idx >> 7, n = idx & 127;
        float iv = g3[n] * rsqrtf(v3[n] + BN_EPS);
        bool flip = (iv < 0.f);
        int kw = q >> 2, ci0 = (q & 3) * 16;
        u32 wd[4] = {0, 0, 0, 0};
        for (int j = 0; j < 16; ++j) {
            int ci = ci0 + j;
            bool pos = (w3[(n * 64 + ci) * 3 + kw] >= 0.f) != flip;
            u32 byte = pos ? 0x01u : 0xFFu;
            wd[j >> 2] |= byte << (8 * (j & 3));
        }
        b3i8[idx] = make_uint4(wd[0], wd[1], wd[2], wd[3]);
    } else if (t < 2464) {
        int co = t - 2336;
        float iv = g3[co] * rsqrtf(v3[co] + BN_EPS);
        float sh = be3[co] - m3[co] * iv;
        float B = b3[co];
        int C = 1000;
        if (iv >= 0.f) {
            for (int v = -192; v <= 192; v += 2)
                if (bn_eval((float)v, B, iv, sh) >= 0.f) { C = v; break; }
        } else {
            for (int v = 192; v >= -192; v -= 2)
                if (bn_eval((float)v, B, iv, sh) >= 0.f) { C = -v; break; }
        }
        C3[co] = C;
    } else if (t < 4000) {
        int idx = t - 2464;
        int j = idx & 1, ch = idx >> 1;
        int co = ch / 6, h = ch % 6;
        float iv = g4[co] * rsqrtf(v4[co] + BN_EPS);
        bool flip = (iv < 0.f);
        u64 wb = 0;
        for (int cb = 0; cb < 64; ++cb) {
            int ci = j * 64 + cb;
            wb |= (u64)((w4[(co * 128 + ci) * 6 + h] >= 0.f) != flip) << cb;
        }
        wt4[idx] = wb;
    } else if (t < 4128) {
        int co = t - 4000;
        float iv = g4[co] * rsqrtf(v4[co] + BN_EPS);
        float sh = be4[co] - m4[co] * iv;
        float B = b4[co];
        bool flip = (iv < 0.f);
        int T = -1;
        for (int p = 0; p <= 768; ++p) {
            int conv = flip ? (2 * p - 768) : (768 - 2 * p);
            float y = bn_eval((float)conv, B, iv, sh);
            if ((y >= 0.f) && (T == p - 1)) T = p;
        }
        T4[co] = T;
    } else if (t < 4448) {
        int idx = t - 4128;
        int o = idx / 32, wi = idx % 32;
        u64 wb = 0;
        for (int fb = 0; fb < 64; ++fb)
            wb |= (u64)(wf[o * 2048 + wi * 64 + fb] >= 0.f) << fb;
        wtf[idx] = wb;
    }
}

// ---------------- fused L1+L2+L3: row-local chain, a1/a2 in LDS only ----------------
// Block = 24 rows. LDS trimmed to 39936 B (<40 KB) so 4 blocks/CU co-reside:
// sX 140 cols (max window index 139), int16 thresholds (lossless ranges).
#define RB 24
__global__ __launch_bounds__(256, 4) void mega123_kernel(
    const float* __restrict__ x, const float4* __restrict__ s1p, const float* __restrict__ T1g,
    const uint4* __restrict__ wt2v, const int* __restrict__ T2g,
    const uint4* __restrict__ b3i8, const int* __restrict__ C3g,
    u32* __restrict__ a3u32) {
    __shared__ uint4 sB3[1536];     // 24576 B
    __shared__ u64 sLUT[256];       // 2048 B
    __shared__ short sC3[128];      // 256 B
    __shared__ uint4 sW2[64];       // 1024 B
    __shared__ short sT2[192];      // 384 B
    __shared__ float sX[8][140];    // 4480 B
    __shared__ u32 sA1[8][32];      // 1024 B
    __shared__ u64 sA2[RB][32];     // 6144 B   => total 39936 B
    int t = threadIdx.x;
    for (int i = t; i < 1536; i += 256) sB3[i] = b3i8[i];
    {
        u32 b = t & 255;
        u64 e = 0;
#pragma unroll
        for (int j = 0; j < 8; ++j)
            e |= (((b >> j) & 1) ? 0x01ull : 0xFFull) << (8 * j);
        if (t < 256) sLUT[t] = e;
    }
    if (t < 128) sC3[t] = (short)C3g[t];
    if (t < 64) sW2[t] = wt2v[t];
    if (t < 192) sT2[t] = (short)T2g[t];

    int co = t & 31, lane = t & 63;
    float4 wa = s1p[co * 3 + 0];
    float4 wb = s1p[co * 3 + 1];
    float wc = s1p[co * 3 + 2].x;
    float Tt = T1g[co];

    int bh0 = blockIdx.x * RB;
    for (int ch = 0; ch < 3; ++ch) {
        __syncthreads();                       // protect sX/sA1 reuse across chunks
        for (int i = t; i < 8 * 140; i += 256) {
            int r = i / 140, c = i % 140;
            float v = 0.f;
            if (c >= 4 && c < 132) v = x[(size_t)(bh0 + ch * 8 + r) * 128 + (c - 4)];
            sX[r][c] = v;
        }
        __syncthreads();
        // ----- L1 (verified body; output to LDS with same lane mapping) -----
        {
            int rr = t >> 5;
            const float* xr = sX[rr];
            float4 A0 = *(const float4*)&xr[0];
            float4 A1 = *(const float4*)&xr[4];
            float4 A2 = *(const float4*)&xr[8];
            u32 myword = 0;
#pragma unroll
            for (int wp = 0; wp < 32; ++wp) {
                float sum0 = 0.f, sum1 = 0.f;
                sum0 = fmaf(wa.x, A0.x, sum0);  sum1 = fmaf(wa.x, A0.z, sum1);
                sum0 = fmaf(wa.y, A0.y, sum0);  sum1 = fmaf(wa.y, A0.w, sum1);
                sum0 = fmaf(wa.z, A0.z, sum0);  sum1 = fmaf(wa.z, A1.x, sum1);
                sum0 = fmaf(wa.w, A0.w, sum0);  sum1 = fmaf(wa.w, A1.y, sum1);
                sum0 = fmaf(wb.x, A1.x, sum0);  sum1 = fmaf(wb.x, A1.z, sum1);
                sum0 = fmaf(wb.y, A1.y, sum0);  sum1 = fmaf(wb.y, A1.w, sum1);
                sum0 = fmaf(wb.z, A1.z, sum0);  sum1 = fmaf(wb.z, A2.x, sum1);
                sum0 = fmaf(wb.w, A1.w, sum0);  sum1 = fmaf(wb.w, A2.y, sum1);
                sum0 = fmaf(wc,   A2.x, sum0);  sum1 = fmaf(wc,   A2.z, sum1);
                bool pred = fmaxf(sum0, sum1) >= Tt;
                u64 mk = __ballot(pred);
                u32 hw = (lane < 32) ? (u32)mk : (u32)(mk >> 32);
                if ((lane & 31) == wp) myword = hw;
                A0 = A1; A1 = A2;
                A2 = *(const float4*)&xr[4 * wp + 12];   // wp=31 -> [136..139], in-bounds
            }
            sA1[((t >> 6) << 1) + (lane >> 5)][lane & 31] = myword;
        }
        __syncthreads();
        // ----- L2 (verified body; LDS in, LDS out) -----
        {
            int r = t >> 5, wp = t & 31;
            u32 am = sA1[r][wp];
            u32 al = (wp > 0) ? sA1[r][wp - 1] : 0u;
            u32 ar = (wp < 31) ? sA1[r][wp + 1] : 0u;
            const short* Tp = &sT2[(wp == 0) ? 64 : ((wp == 31) ? 128 : 0)];
            u64 word2 = 0;
#pragma unroll
            for (int c = 0; c < 64; ++c) {
                uint4 w2v = sW2[c];
                int p = __popc(al ^ w2v.x) + __popc(am ^ w2v.y) + __popc(ar ^ w2v.z);
                word2 |= (u64)(p <= (int)Tp[c]) << c;
            }
            sA2[ch * 8 + r][wp] = word2;
        }
    }
    __syncthreads();

    // ----- L3 (verified MFMA body; neighbors via guarded LDS reads) -----
    int wq = t >> 6, m = lane & 31, half = lane >> 5;
    const int prTab[8] = {0, 1, 4, 5, 8, 9, 12, 13};
    for (int r6 = 0; r6 < 6; ++r6) {
        int row = wq * 6 + r6;
        u64 aw = sA2[row][m];
        u64 wm1 = (m > 0) ? sA2[row][m - 1] : 0ull;
        u64 wp1 = (m < 31) ? sA2[row][m + 1] : 0ull;

        v4i A[6];
#pragma unroll
        for (int kk = 0; kk < 6; ++kk) {
            const int kw = kk >> 1;
            u64 word = (kw == 0) ? wm1 : ((kw == 1) ? aw : wp1);
            bool valid = !((kw == 0 && m == 0) || (kw == 2 && m == 31));
            int ci0 = ((kk & 1) << 5) + (half << 4);
            u32 bits = (u32)(word >> ci0) & 0xFFFFu;
            u64 lo = sLUT[bits & 0xFF];
            u64 hi = sLUT[bits >> 8];
            if (!valid) { lo = 0; hi = 0; }
            union { u64 q[2]; v4i v; } u;
            u.q[0] = lo; u.q[1] = hi;
            A[kk] = u.v;
        }
        u32 outv = 0;
#pragma unroll
        for (int nt = 0; nt < 4; ++nt) {
            v16i acc;
#pragma unroll
            for (int i = 0; i < 16; ++i) acc[i] = 0;
#pragma unroll
            for (int kk = 0; kk < 6; ++kk) {
                int q = kk * 2 + half;
                union { uint4 u4; v4i v; } bu;
                bu.u4 = sB3[q * 128 + nt * 32 + m];
                acc = __builtin_amdgcn_mfma_i32_32x32x32_i8(A[kk], bu.v, acc, 0, 0, 0);
            }
            int tc = (int)sC3[nt * 32 + m];
#pragma unroll
            for (int rp = 0; rp < 8; ++rp) {
                bool c = (acc[2 * rp] >= tc) || (acc[2 * rp + 1] >= tc);
                u64 mk = __ballot(c);
                int LA = (nt << 4) | prTab[rp];
                int LB = LA + 2;
                outv = (lane == LA) ? (u32)mk : outv;
                outv = (lane == LB) ? (u32)(mk >> 32) : outv;
            }
        }
        a3u32[(size_t)(bh0 + row) * 64 + ((lane & 15) << 2) + (lane >> 4)] = outv;
    }
}

// ---------------- layer 4 (6x1 conv) + FC (2048->10), verified ----------------
__global__ __launch_bounds__(256) void layer4_fc_kernel(
    const u64* __restrict__ a3, const u64* __restrict__ wt4, const int* __restrict__ T4,
    const u64* __restrict__ wtf, const float* __restrict__ bf, float* __restrict__ out) {
    __shared__ u64 sW4[1536];
    __shared__ u64 sWf[320];
    __shared__ u64 sFeat[16][32];
    __shared__ int sT[128];
    __shared__ float sBf[10];
    int t = threadIdx.x;
    {
        ulonglong2* d = (ulonglong2*)sW4;
        const ulonglong2* s = (const ulonglong2*)wt4;
        for (int i = t; i < 768; i += 256) d[i] = s[i];
        ulonglong2* df = (ulonglong2*)sWf;
        const ulonglong2* sf = (const ulonglong2*)wtf;
        if (t < 160) df[t] = sf[t];
    }
    if (t < 128) sT[t] = T4[t];
    if (t < 10) sBf[t] = bf[t];
    __syncthreads();
    int bb = t >> 4, w = t & 15, lane = t & 63, g = lane >> 4;
    int b = blockIdx.x * 16 + bb;
    u64 av[12];
#pragma unroll
    for (int h = 0; h < 6; ++h) {
        av[h * 2 + 0] = a3[(size_t)b * 192 + h * 32 + w * 2 + 0];
        av[h * 2 + 1] = a3[(size_t)b * 192 + h * 32 + w * 2 + 1];
    }
    u64 acc = 0;
#pragma unroll 8
    for (int c = 0; c < 128; ++c) {
        const u64* wr = &sW4[c * 12];
        int p = 0;
#pragma unroll
        for (int q = 0; q < 12; ++q) p += __popcll(av[q] ^ wr[q]);
        u64 mk = __ballot(p <= sT[c]);
        u64 field = (mk >> (g * 16)) & 0xFFFFull;
        acc |= field << ((c & 3) << 4);
        if ((c & 3) == 3) {
            if (w == 0) sFeat[bb][c >> 2] = acc;
            acc = 0;
        }
    }
    __syncthreads();
    if (t < 160) {
        int fb = t / 10, o = t % 10;
        int p = 0;
#pragma unroll
        for (int wi = 0; wi < 32; ++wi) p += __popcll(sFeat[fb][wi] ^ sWf[o * 32 + wi]);
        out[(size_t)(blockIdx.x * 16 + fb) * 10 + o] = __fadd_rn((float)(2048 - 2 * p), sBf[o]);
    }
}

// ---------------- launch ----------------
extern "C" void kernel_launch(void* const* d_in, const int* in_sizes, int n_in,
                              void* d_out, int out_size, void* d_ws, size_t ws_size,
                              hipStream_t stream) {
    const float* x  = (const float*)d_in[0];
    const float* w1 = (const float*)d_in[1];  const float* b1 = (const float*)d_in[2];
    const float* w2 = (const float*)d_in[3];  const float* b2 = (const float*)d_in[4];
    const float* w3 = (const float*)d_in[5];  const float* b3 = (const float*)d_in[6];
    const float* w4 = (const float*)d_in[7];  const float* b4 = (const float*)d_in[8];
    const float* g1 = (const float*)d_in[9];  const float* be1 = (const float*)d_in[10];
    const float* m1 = (const float*)d_in[11]; const float* v1 = (const float*)d_in[12];
    const float* g2 = (const float*)d_in[13]; const float* be2 = (const float*)d_in[14];
    const float* m2 = (const float*)d_in[15]; const float* v2 = (const float*)d_in[16];
    const float* g3 = (const float*)d_in[17]; const float* be3 = (const float*)d_in[18];
    const float* m3 = (const float*)d_in[19]; const float* v3 = (const float*)d_in[20];
    const float* g4 = (const float*)d_in[21]; const float* be4 = (const float*)d_in[22];
    const float* m4 = (const float*)d_in[23]; const float* v4 = (const float*)d_in[24];
    const float* wf = (const float*)d_in[25]; const float* bf = (const float*)d_in[26];
    float* out = (float*)d_out;

    char* ws = (char*)d_ws;
    u64* a3 = (u64*)(ws + 0);                 // 8192*6*16*2 u64 = 12582912 B
    const size_t S = 12582912;
    uint4* b3i8 = (uint4*)(ws + S + 0);       // 24576 B
    u64*  wt4  = (u64*) (ws + S + 24576);     // 12288 B
    u64*  wtf  = (u64*) (ws + S + 36864);     // 2560 B
    u32*  wt2w = (u32*) (ws + S + 39424);     // 1024 B
    float* s1f = (float*)(ws + S + 40448);    // 1536 B
    float* T1  = (float*)(ws + S + 41984);    // 128 B
    int*  T2   = (int*)  (ws + S + 42112);    // 768 B
    int*  C3   = (int*)  (ws + S + 42880);    // 512 B
    int*  T4   = (int*)  (ws + S + 43392);    // 512 B

    prep_all<<<18, 256, 0, stream>>>(w1, b1, w2, b2, w3, b3, w4, b4, wf,
                                     g1, be1, m1, v1, g2, be2, m2, v2,
                                     g3, be3, m3, v3, g4, be4, m4, v4,
                                     s1f, T1, wt2w, T2, b3i8, C3, wt4, T4, wtf);

    mega123_kernel<<<(BATCH * 6) / RB, 256, 0, stream>>>(
        x, (const float4*)s1f, T1, (const uint4*)wt2w, T2, b3i8, C3, (u32*)a3);
    layer4_fc_kernel<<<BATCH / 16, 256, 0, stream>>>(a3, wt4, T4, wtf, bf, out);
}

// Round 12
// 270.267 us; speedup vs baseline: 1.0187x; 1.0187x over previous
//
#include <hip/hip_runtime.h>
#include <cstdint>
#include <cstddef>

#define BN_EPS 1e-5f
#define BATCH 8192

typedef unsigned long long u64;
typedef uint32_t u32;
typedef int v4i __attribute__((ext_vector_type(4)));
typedef int v16i __attribute__((ext_vector_type(16)));

// float <-> total-order key (ascending with float order on finites)
__device__ __forceinline__ u32 f2k(float f) {
    u32 u = __float_as_uint(f);
    return (u >> 31) ? ~u : (u | 0x80000000u);
}
__device__ __forceinline__ float k2f(u32 k) {
    u32 u = (k & 0x80000000u) ? (k ^ 0x80000000u) : ~k;
    return __uint_as_float(u);
}
// exact fp32 BN chain — bit-identical to the reference epilogue semantics
__device__ __forceinline__ float bn_eval(float conv, float B, float iv, float sh) {
    return __fadd_rn(__fmul_rn(__fadd_rn(conv, B), iv), sh);
}

// ---------------- one merged prep kernel (R8-verified) ----------------
__global__ __launch_bounds__(256) void prep_all(
    const float* w1, const float* b1, const float* w2, const float* b2,
    const float* w3, const float* b3, const float* w4, const float* b4,
    const float* wf,
    const float* g1, const float* be1, const float* m1, const float* v1,
    const float* g2, const float* be2, const float* m2, const float* v2,
    const float* g3, const float* be3, const float* m3, const float* v3,
    const float* g4, const float* be4, const float* m4, const float* v4,
    float* s1f, float* T1, u32* wt2w, int* T2,
    uint4* b3i8, int* C3, u64* wt4, int* T4, u64* wtf) {
    int t = blockIdx.x * 256 + threadIdx.x;

    if (t < 384) {
        int co = t / 12, k = t % 12;
        float val = 0.f;
        if (k < 9) {
            float iv = g1[co] * rsqrtf(v1[co] + BN_EPS);
            float d = (iv < 0.f) ? -1.f : 1.f;
            val = ((w1[co * 9 + k] >= 0.f) ? 1.f : -1.f) * d;
        }
        s1f[t] = val;
    } else if (t < 416) {
        int co = t - 384;
        float iv = g1[co] * rsqrtf(v1[co] + BN_EPS);
        float sh = be1[co] - m1[co] * iv;
        float B = b1[co];
        bool flip = (iv < 0.f);
        auto pred = [&](float sp) {
            float sum = flip ? -sp : sp;
            return bn_eval(sum, B, iv, sh) >= 0.f;
        };
        u32 lo = f2k(-3.0e38f), hi = f2k(3.0e38f);
        float Tv;
        if (pred(k2f(lo))) Tv = k2f(lo);
        else if (!pred(k2f(hi))) Tv = __uint_as_float(0x7F800000u);
        else {
            while (hi - lo > 1u) {
                u32 mid = lo + ((hi - lo) >> 1);
                if (pred(k2f(mid))) hi = mid; else lo = mid;
            }
            Tv = k2f(hi);
        }
        T1[co] = Tv;
    } else if (t < 608) {
        int idx = t - 416;
        int co = idx / 3, kw = idx % 3;
        float iv = g2[co] * rsqrtf(v2[co] + BN_EPS);
        bool flip = (iv < 0.f);
        u32 wb = 0;
        for (int ci = 0; ci < 32; ++ci)
            wb |= (u32)((w2[(co * 32 + ci) * 3 + kw] >= 0.f) != flip) << ci;
        wt2w[co * 4 + kw] = wb;
    } else if (t < 800) {
        int idx = t - 608;
        int co = idx & 63, cls = idx >> 6;
        float iv = g2[co] * rsqrtf(v2[co] + BN_EPS);
        float sh = be2[co] - m2[co] * iv;
        float B = b2[co];
        bool flip = (iv < 0.f);
        int spur = 0, nv = 3;
        if (cls == 1) { nv = 2; for (int ci = 0; ci < 32; ++ci) spur += (int)((w2[(co * 32 + ci) * 3 + 0] >= 0.f) != flip); }
        if (cls == 2) { nv = 2; for (int ci = 0; ci < 32; ++ci) spur += (int)((w2[(co * 32 + ci) * 3 + 2] >= 0.f) != flip); }
        int maxp = 32 * nv + spur;
        int T = -1;
        for (int p = 0; p <= maxp; ++p) {
            int conv = flip ? (2 * (p - spur) - 32 * nv) : (32 * nv - 2 * (p - spur));
            float y = bn_eval((float)conv, B, iv, sh);
            if ((y >= 0.f) && (T == p - 1)) T = p;
        }
        T2[cls * 64 + co] = T;
    } else if (t < 2336) {
        int idx = t - 800;
        int q = idx >> 7, n = idx & 127;
        float iv = g3[n] * rsqrtf(v3[n] + BN_EPS);
        bool flip = (iv < 0.f);
        int kw = q >> 2, ci0 = (q & 3) * 16;
        u32 wd[4] = {0, 0, 0, 0};
        for (int j = 0; j < 16; ++j) {
            int ci = ci0 + j;
            bool pos = (w3[(n * 64 + ci) * 3 + kw] >= 0.f) != flip;
            u32 byte = pos ? 0x01u : 0xFFu;
            wd[j >> 2] |= byte << (8 * (j & 3));
        }
        b3i8[idx] = make_uint4(wd[0], wd[1], wd[2], wd[3]);
    } else if (t < 2464) {
        int co = t - 2336;
        float iv = g3[co] * rsqrtf(v3[co] + BN_EPS);
        float sh = be3[co] - m3[co] * iv;
        float B = b3[co];
        int C = 1000;
        if (iv >= 0.f) {
            for (int v = -192; v <= 192; v += 2)
                if (bn_eval((float)v, B, iv, sh) >= 0.f) { C = v; break; }
        } else {
            for (int v = 192; v >= -192; v -= 2)
                if (bn_eval((float)v, B, iv, sh) >= 0.f) { C = -v; break; }
        }
        C3[co] = C;
    } else if (t < 4000) {
        int idx = t - 2464;
        int j = idx & 1, ch = idx >> 1;
        int co = ch / 6, h = ch % 6;
        float iv = g4[co] * rsqrtf(v4[co] + BN_EPS);
        bool flip = (iv < 0.f);
        u64 wb = 0;
        for (int cb = 0; cb < 64; ++cb) {
            int ci = j * 64 + cb;
            wb |= (u64)((w4[(co * 128 + ci) * 6 + h] >= 0.f) != flip) << cb;
        }
        wt4[idx] = wb;
    } else if (t < 4128) {
        int co = t - 4000;
        float iv = g4[co] * rsqrtf(v4[co] + BN_EPS);
        float sh = be4[co] - m4[co] * iv;
        float B = b4[co];
        bool flip = (iv < 0.f);
        int T = -1;
        for (int p = 0; p <= 768; ++p) {
            int conv = flip ? (2 * p - 768) : (768 - 2 * p);
            float y = bn_eval((float)conv, B, iv, sh);
            if ((y >= 0.f) && (T == p - 1)) T = p;
        }
        T4[co] = T;
    } else if (t < 4448) {
        int idx = t - 4128;
        int o = idx / 32, wi = idx % 32;
        u64 wb = 0;
        for (int fb = 0; fb < 64; ++fb)
            wb |= (u64)(wf[o * 2048 + wi * 64 + fb] >= 0.f) << fb;
        wtf[idx] = wb;
    }
}

// ---------------- fused L1+L2+L3: row-local chain, a1/a2 in LDS only ----------------
// Block = 24 rows. LDS 39936 B (<40 KB: 4 blocks/CU by LDS). launch_bounds
// min-waves=3 so the allocator keeps the no-spill ~76-VGPR allocation
// (R11's =4 forced 64 VGPR -> 53 MB scratch spill traffic, net loss).
#define RB 24
__global__ __launch_bounds__(256, 3) void mega123_kernel(
    const float* __restrict__ x, const float4* __restrict__ s1p, const float* __restrict__ T1g,
    const uint4* __restrict__ wt2v, const int* __restrict__ T2g,
    const uint4* __restrict__ b3i8, const int* __restrict__ C3g,
    u32* __restrict__ a3u32) {
    __shared__ uint4 sB3[1536];     // 24576 B
    __shared__ u64 sLUT[256];       // 2048 B
    __shared__ short sC3[128];      // 256 B
    __shared__ uint4 sW2[64];       // 1024 B
    __shared__ short sT2[192];      // 384 B
    __shared__ float sX[8][140];    // 4480 B
    __shared__ u32 sA1[8][32];      // 1024 B
    __shared__ u64 sA2[RB][32];     // 6144 B   => total 39936 B
    int t = threadIdx.x;
    for (int i = t; i < 1536; i += 256) sB3[i] = b3i8[i];
    {
        u32 b = t & 255;
        u64 e = 0;
#pragma unroll
        for (int j = 0; j < 8; ++j)
            e |= (((b >> j) & 1) ? 0x01ull : 0xFFull) << (8 * j);
        if (t < 256) sLUT[t] = e;
    }
    if (t < 128) sC3[t] = (short)C3g[t];
    if (t < 64) sW2[t] = wt2v[t];
    if (t < 192) sT2[t] = (short)T2g[t];

    int co = t & 31, lane = t & 63;
    float4 wa = s1p[co * 3 + 0];
    float4 wb = s1p[co * 3 + 1];
    float wc = s1p[co * 3 + 2].x;
    float Tt = T1g[co];

    int bh0 = blockIdx.x * RB;
    for (int ch = 0; ch < 3; ++ch) {
        __syncthreads();                       // protect sX/sA1 reuse across chunks
        for (int i = t; i < 8 * 140; i += 256) {
            int r = i / 140, c = i % 140;
            float v = 0.f;
            if (c >= 4 && c < 132) v = x[(size_t)(bh0 + ch * 8 + r) * 128 + (c - 4)];
            sX[r][c] = v;
        }
        __syncthreads();
        // ----- L1 (verified body; output to LDS with same lane mapping) -----
        {
            int rr = t >> 5;
            const float* xr = sX[rr];
            float4 A0 = *(const float4*)&xr[0];
            float4 A1 = *(const float4*)&xr[4];
            float4 A2 = *(const float4*)&xr[8];
            u32 myword = 0;
#pragma unroll
            for (int wp = 0; wp < 32; ++wp) {
                float sum0 = 0.f, sum1 = 0.f;
                sum0 = fmaf(wa.x, A0.x, sum0);  sum1 = fmaf(wa.x, A0.z, sum1);
                sum0 = fmaf(wa.y, A0.y, sum0);  sum1 = fmaf(wa.y, A0.w, sum1);
                sum0 = fmaf(wa.z, A0.z, sum0);  sum1 = fmaf(wa.z, A1.x, sum1);
                sum0 = fmaf(wa.w, A0.w, sum0);  sum1 = fmaf(wa.w, A1.y, sum1);
                sum0 = fmaf(wb.x, A1.x, sum0);  sum1 = fmaf(wb.x, A1.z, sum1);
                sum0 = fmaf(wb.y, A1.y, sum0);  sum1 = fmaf(wb.y, A1.w, sum1);
                sum0 = fmaf(wb.z, A1.z, sum0);  sum1 = fmaf(wb.z, A2.x, sum1);
                sum0 = fmaf(wb.w, A1.w, sum0);  sum1 = fmaf(wb.w, A2.y, sum1);
                sum0 = fmaf(wc,   A2.x, sum0);  sum1 = fmaf(wc,   A2.z, sum1);
                bool pred = fmaxf(sum0, sum1) >= Tt;
                u64 mk = __ballot(pred);
                u32 hw = (lane < 32) ? (u32)mk : (u32)(mk >> 32);
                if ((lane & 31) == wp) myword = hw;
                A0 = A1; A1 = A2;
                A2 = *(const float4*)&xr[4 * wp + 12];   // wp=31 -> [136..139], in-bounds
            }
            sA1[((t >> 6) << 1) + (lane >> 5)][lane & 31] = myword;
        }
        __syncthreads();
        // ----- L2 (verified body; LDS in, LDS out) -----
        {
            int r = t >> 5, wp = t & 31;
            u32 am = sA1[r][wp];
            u32 al = (wp > 0) ? sA1[r][wp - 1] : 0u;
            u32 ar = (wp < 31) ? sA1[r][wp + 1] : 0u;
            const short* Tp = &sT2[(wp == 0) ? 64 : ((wp == 31) ? 128 : 0)];
            u64 word2 = 0;
#pragma unroll
            for (int c = 0; c < 64; ++c) {
                uint4 w2v = sW2[c];
                int p = __popc(al ^ w2v.x) + __popc(am ^ w2v.y) + __popc(ar ^ w2v.z);
                word2 |= (u64)(p <= (int)Tp[c]) << c;
            }
            sA2[ch * 8 + r][wp] = word2;
        }
    }
    __syncthreads();

    // ----- L3 (verified MFMA body; neighbors via guarded LDS reads) -----
    int wq = t >> 6, m = lane & 31, half = lane >> 5;
    const int prTab[8] = {0, 1, 4, 5, 8, 9, 12, 13};
    for (int r6 = 0; r6 < 6; ++r6) {
        int row = wq * 6 + r6;
        u64 aw = sA2[row][m];
        u64 wm1 = (m > 0) ? sA2[row][m - 1] : 0ull;
        u64 wp1 = (m < 31) ? sA2[row][m + 1] : 0ull;

        v4i A[6];
#pragma unroll
        for (int kk = 0; kk < 6; ++kk) {
            const int kw = kk >> 1;
            u64 word = (kw == 0) ? wm1 : ((kw == 1) ? aw : wp1);
            bool valid = !((kw == 0 && m == 0) || (kw == 2 && m == 31));
            int ci0 = ((kk & 1) << 5) + (half << 4);
            u32 bits = (u32)(word >> ci0) & 0xFFFFu;
            u64 lo = sLUT[bits & 0xFF];
            u64 hi = sLUT[bits >> 8];
            if (!valid) { lo = 0; hi = 0; }
            union { u64 q[2]; v4i v; } u;
            u.q[0] = lo; u.q[1] = hi;
            A[kk] = u.v;
        }
        u32 outv = 0;
#pragma unroll
        for (int nt = 0; nt < 4; ++nt) {
            v16i acc;
#pragma unroll
            for (int i = 0; i < 16; ++i) acc[i] = 0;
#pragma unroll
            for (int kk = 0; kk < 6; ++kk) {
                int q = kk * 2 + half;
                union { uint4 u4; v4i v; } bu;
                bu.u4 = sB3[q * 128 + nt * 32 + m];
                acc = __builtin_amdgcn_mfma_i32_32x32x32_i8(A[kk], bu.v, acc, 0, 0, 0);
            }
            int tc = (int)sC3[nt * 32 + m];
#pragma unroll
            for (int rp = 0; rp < 8; ++rp) {
                bool c = (acc[2 * rp] >= tc) || (acc[2 * rp + 1] >= tc);
                u64 mk = __ballot(c);
                int LA = (nt << 4) | prTab[rp];
                int LB = LA + 2;
                outv = (lane == LA) ? (u32)mk : outv;
                outv = (lane == LB) ? (u32)(mk >> 32) : outv;
            }
        }
        a3u32[(size_t)(bh0 + row) * 64 + ((lane & 15) << 2) + (lane >> 4)] = outv;
    }
}

// ---------------- layer 4 (6x1 conv) + FC (2048->10), verified ----------------
__global__ __launch_bounds__(256) void layer4_fc_kernel(
    const u64* __restrict__ a3, const u64* __restrict__ wt4, const int* __restrict__ T4,
    const u64* __restrict__ wtf, const float* __restrict__ bf, float* __restrict__ out) {
    __shared__ u64 sW4[1536];
    __shared__ u64 sWf[320];
    __shared__ u64 sFeat[16][32];
    __shared__ int sT[128];
    __shared__ float sBf[10];
    int t = threadIdx.x;
    {
        ulonglong2* d = (ulonglong2*)sW4;
        const ulonglong2* s = (const ulonglong2*)wt4;
        for (int i = t; i < 768; i += 256) d[i] = s[i];
        ulonglong2* df = (ulonglong2*)sWf;
        const ulonglong2* sf = (const ulonglong2*)wtf;
        if (t < 160) df[t] = sf[t];
    }
    if (t < 128) sT[t] = T4[t];
    if (t < 10) sBf[t] = bf[t];
    __syncthreads();
    int bb = t >> 4, w = t & 15, lane = t & 63, g = lane >> 4;
    int b = blockIdx.x * 16 + bb;
    u64 av[12];
#pragma unroll
    for (int h = 0; h < 6; ++h) {
        av[h * 2 + 0] = a3[(size_t)b * 192 + h * 32 + w * 2 + 0];
        av[h * 2 + 1] = a3[(size_t)b * 192 + h * 32 + w * 2 + 1];
    }
    u64 acc = 0;
#pragma unroll 8
    for (int c = 0; c < 128; ++c) {
        const u64* wr = &sW4[c * 12];
        int p = 0;
#pragma unroll
        for (int q = 0; q < 12; ++q) p += __popcll(av[q] ^ wr[q]);
        u64 mk = __ballot(p <= sT[c]);
        u64 field = (mk >> (g * 16)) & 0xFFFFull;
        acc |= field << ((c & 3) << 4);
        if ((c & 3) == 3) {
            if (w == 0) sFeat[bb][c >> 2] = acc;
            acc = 0;
        }
    }
    __syncthreads();
    if (t < 160) {
        int fb = t / 10, o = t % 10;
        int p = 0;
#pragma unroll
        for (int wi = 0; wi < 32; ++wi) p += __popcll(sFeat[fb][wi] ^ sWf[o * 32 + wi]);
        out[(size_t)(blockIdx.x * 16 + fb) * 10 + o] = __fadd_rn((float)(2048 - 2 * p), sBf[o]);
    }
}

// ---------------- launch ----------------
extern "C" void kernel_launch(void* const* d_in, const int* in_sizes, int n_in,
                              void* d_out, int out_size, void* d_ws, size_t ws_size,
                              hipStream_t stream) {
    const float* x  = (const float*)d_in[0];
    const float* w1 = (const float*)d_in[1];  const float* b1 = (const float*)d_in[2];
    const float* w2 = (const float*)d_in[3];  const float* b2 = (const float*)d_in[4];
    const float* w3 = (const float*)d_in[5];  const float* b3 = (const float*)d_in[6];
    const float* w4 = (const float*)d_in[7];  const float* b4 = (const float*)d_in[8];
    const float* g1 = (const float*)d_in[9];  const float* be1 = (const float*)d_in[10];
    const float* m1 = (const float*)d_in[11]; const float* v1 = (const float*)d_in[12];
    const float* g2 = (const float*)d_in[13]; const float* be2 = (const float*)d_in[14];
    const float* m2 = (const float*)d_in[15]; const float* v2 = (const float*)d_in[16];
    const float* g3 = (const float*)d_in[17]; const float* be3 = (const float*)d_in[18];
    const float* m3 = (const float*)d_in[19]; const float* v3 = (const float*)d_in[20];
    const float* g4 = (const float*)d_in[21]; const float* be4 = (const float*)d_in[22];
    const float* m4 = (const float*)d_in[23]; const float* v4 = (const float*)d_in[24];
    const float* wf = (const float*)d_in[25]; const float* bf = (const float*)d_in[26];
    float* out = (float*)d_out;

    char* ws = (char*)d_ws;
    u64* a3 = (u64*)(ws + 0);                 // 8192*6*16*2 u64 = 12582912 B
    const size_t S = 12582912;
    uint4* b3i8 = (uint4*)(ws + S + 0);       // 24576 B
    u64*  wt4  = (u64*) (ws + S + 24576);     // 12288 B
    u64*  wtf  = (u64*) (ws + S + 36864);     // 2560 B
    u32*  wt2w = (u32*) (ws + S + 39424);     // 1024 B
    float* s1f = (float*)(ws + S + 40448);    // 1536 B
    float* T1  = (float*)(ws + S + 41984);    // 128 B
    int*  T2   = (int*)  (ws + S + 42112);    // 768 B
    int*  C3   = (int*)  (ws + S + 42880);    // 512 B
    int*  T4   = (int*)  (ws + S + 43392);    // 512 B

    prep_all<<<18, 256, 0, stream>>>(w1, b1, w2, b2, w3, b3, w4, b4, wf,
                                     g1, be1, m1, v1, g2, be2, m2, v2,
                                     g3, be3, m3, v3, g4, be4, m4, v4,
                                     s1f, T1, wt2w, T2, b3i8, C3, wt4, T4, wtf);

    mega123_kernel<<<(BATCH * 6) / RB, 256, 0, stream>>>(
        x, (const float4*)s1f, T1, (const uint4*)wt2w, T2, b3i8, C3, (u32*)a3);
    layer4_fc_kernel<<<BATCH / 16, 256, 0, stream>>>(a3, wt4, T4, wtf, bf, out);
}

// Round 13
// 256.532 us; speedup vs baseline: 1.0733x; 1.0535x over previous
//
#include <hip/hip_runtime.h>
#include <cstdint>
#include <cstddef>

#define BN_EPS 1e-5f
#define BATCH 8192

typedef unsigned long long u64;
typedef uint32_t u32;
typedef int v4i __attribute__((ext_vector_type(4)));
typedef int v16i __attribute__((ext_vector_type(16)));

// float <-> total-order key (ascending with float order on finites)
__device__ __forceinline__ u32 f2k(float f) {
    u32 u = __float_as_uint(f);
    return (u >> 31) ? ~u : (u | 0x80000000u);
}
__device__ __forceinline__ float k2f(u32 k) {
    u32 u = (k & 0x80000000u) ? (k ^ 0x80000000u) : ~k;
    return __uint_as_float(u);
}
// exact fp32 BN chain — bit-identical to the reference epilogue semantics
__device__ __forceinline__ float bn_eval(float conv, float B, float iv, float sh) {
    return __fadd_rn(__fmul_rn(__fadd_rn(conv, B), iv), sh);
}

// ---------------- one merged prep kernel (R8-verified) ----------------
__global__ __launch_bounds__(256) void prep_all(
    const float* w1, const float* b1, const float* w2, const float* b2,
    const float* w3, const float* b3, const float* w4, const float* b4,
    const float* wf,
    const float* g1, const float* be1, const float* m1, const float* v1,
    const float* g2, const float* be2, const float* m2, const float* v2,
    const float* g3, const float* be3, const float* m3, const float* v3,
    const float* g4, const float* be4, const float* m4, const float* v4,
    float* s1f, float* T1, u32* wt2w, int* T2,
    uint4* b3i8, int* C3, u64* wt4, int* T4, u64* wtf) {
    int t = blockIdx.x * 256 + threadIdx.x;

    if (t < 384) {
        int co = t / 12, k = t % 12;
        float val = 0.f;
        if (k < 9) {
            float iv = g1[co] * rsqrtf(v1[co] + BN_EPS);
            float d = (iv < 0.f) ? -1.f : 1.f;
            val = ((w1[co * 9 + k] >= 0.f) ? 1.f : -1.f) * d;
        }
        s1f[t] = val;
    } else if (t < 416) {
        int co = t - 384;
        float iv = g1[co] * rsqrtf(v1[co] + BN_EPS);
        float sh = be1[co] - m1[co] * iv;
        float B = b1[co];
        bool flip = (iv < 0.f);
        auto pred = [&](float sp) {
            float sum = flip ? -sp : sp;
            return bn_eval(sum, B, iv, sh) >= 0.f;
        };
        u32 lo = f2k(-3.0e38f), hi = f2k(3.0e38f);
        float Tv;
        if (pred(k2f(lo))) Tv = k2f(lo);
        else if (!pred(k2f(hi))) Tv = __uint_as_float(0x7F800000u);
        else {
            while (hi - lo > 1u) {
                u32 mid = lo + ((hi - lo) >> 1);
                if (pred(k2f(mid))) hi = mid; else lo = mid;
            }
            Tv = k2f(hi);
        }
        T1[co] = Tv;
    } else if (t < 608) {
        int idx = t - 416;
        int co = idx / 3, kw = idx % 3;
        float iv = g2[co] * rsqrtf(v2[co] + BN_EPS);
        bool flip = (iv < 0.f);
        u32 wb = 0;
        for (int ci = 0; ci < 32; ++ci)
            wb |= (u32)((w2[(co * 32 + ci) * 3 + kw] >= 0.f) != flip) << ci;
        wt2w[co * 4 + kw] = wb;
    } else if (t < 800) {
        int idx = t - 608;
        int co = idx & 63, cls = idx >> 6;
        float iv = g2[co] * rsqrtf(v2[co] + BN_EPS);
        float sh = be2[co] - m2[co] * iv;
        float B = b2[co];
        bool flip = (iv < 0.f);
        int spur = 0, nv = 3;
        if (cls == 1) { nv = 2; for (int ci = 0; ci < 32; ++ci) spur += (int)((w2[(co * 32 + ci) * 3 + 0] >= 0.f) != flip); }
        if (cls == 2) { nv = 2; for (int ci = 0; ci < 32; ++ci) spur += (int)((w2[(co * 32 + ci) * 3 + 2] >= 0.f) != flip); }
        int maxp = 32 * nv + spur;
        int T = -1;
        for (int p = 0; p <= maxp; ++p) {
            int conv = flip ? (2 * (p - spur) - 32 * nv) : (32 * nv - 2 * (p - spur));
            float y = bn_eval((float)conv, B, iv, sh);
            if ((y >= 0.f) && (T == p - 1)) T = p;
        }
        T2[cls * 64 + co] = T;
    } else if (t < 2336) {
        int idx = t - 800;
        int q = idx >> 7, n = idx & 127;
        float iv = g3[n] * rsqrtf(v3[n] + BN_EPS);
        bool flip = (iv < 0.f);
        int kw = q >> 2, ci0 = (q & 3) * 16;
        u32 wd[4] = {0, 0, 0, 0};
        for (int j = 0; j < 16; ++j) {
            int ci = ci0 + j;
            bool pos = (w3[(n * 64 + ci) * 3 + kw] >= 0.f) != flip;
            u32 byte = pos ? 0x01u : 0xFFu;
            wd[j >> 2] |= byte << (8 * (j & 3));
        }
        b3i8[idx] = make_uint4(wd[0], wd[1], wd[2], wd[3]);
    } else if (t < 2464) {
        int co = t - 2336;
        float iv = g3[co] * rsqrtf(v3[co] + BN_EPS);
        float sh = be3[co] - m3[co] * iv;
        float B = b3[co];
        int C = 1000;
        if (iv >= 0.f) {
            for (int v = -192; v <= 192; v += 2)
                if (bn_eval((float)v, B, iv, sh) >= 0.f) { C = v; break; }
        } else {
            for (int v = 192; v >= -192; v -= 2)
                if (bn_eval((float)v, B, iv, sh) >= 0.f) { C = -v; break; }
        }
        C3[co] = C;
    } else if (t < 4000) {
        int idx = t - 2464;
        int j = idx & 1, ch = idx >> 1;
        int co = ch / 6, h = ch % 6;
        float iv = g4[co] * rsqrtf(v4[co] + BN_EPS);
        bool flip = (iv < 0.f);
        u64 wb = 0;
        for (int cb = 0; cb < 64; ++cb) {
            int ci = j * 64 + cb;
            wb |= (u64)((w4[(co * 128 + ci) * 6 + h] >= 0.f) != flip) << cb;
        }
        wt4[idx] = wb;
    } else if (t < 4128) {
        int co = t - 4000;
        float iv = g4[co] * rsqrtf(v4[co] + BN_EPS);
        float sh = be4[co] - m4[co] * iv;
        float B = b4[co];
        bool flip = (iv < 0.f);
        int T = -1;
        for (int p = 0; p <= 768; ++p) {
            int conv = flip ? (2 * p - 768) : (768 - 2 * p);
            float y = bn_eval((float)conv, B, iv, sh);
            if ((y >= 0.f) && (T == p - 1)) T = p;
        }
        T4[co] = T;
    } else if (t < 4448) {
        int idx = t - 4128;
        int o = idx / 32, wi = idx % 32;
        u64 wb = 0;
        for (int fb = 0; fb < 64; ++fb)
            wb |= (u64)(wf[o * 2048 + wi * 64 + fb] >= 0.f) << fb;
        wtf[idx] = wb;
    }
}

// ---------------- fully-fused L1..L4+FC: one block = 24 rows = 4 batches ----------------
// smem layout (40576 B, phases alias dead regions via raw buffer):
//   [0,24576)     sB3 (L3 weights)          -> after L3: sW4 [0,12288) + sWf [12288,14848)
//   [24576,26624) sLUT
//   [26624,26880) sC3 (short)
//   [26880,27904) sW2                        -> after L3: sFeat u64[4][32]
//   [27904,28288) sT2 (short)                -> after L3: sT4 short[128] + sBf f32[10]
//   [28288,34432) union{ sX f32[8][140] + sA1 u32[8][32] | sA3 u32[24*64] }
//   [34432,40576) sA2 u64[24][32]
#define RB 24
__global__ __launch_bounds__(256, 3) void mega_kernel(
    const float* __restrict__ x, const float4* __restrict__ s1p, const float* __restrict__ T1g,
    const uint4* __restrict__ wt2v, const int* __restrict__ T2g,
    const uint4* __restrict__ b3i8, const int* __restrict__ C3g,
    const u64* __restrict__ wt4, const int* __restrict__ T4g,
    const u64* __restrict__ wtf, const float* __restrict__ bfg,
    float* __restrict__ out) {
    __shared__ __attribute__((aligned(16))) char smem[40576];
    uint4* sB3 = (uint4*)smem;
    u64*  sLUT = (u64*)(smem + 24576);
    short* sC3 = (short*)(smem + 26624);
    uint4* sW2 = (uint4*)(smem + 26880);
    short* sT2 = (short*)(smem + 27904);
    float* sX  = (float*)(smem + 28288);    // [8][140]
    u32*  sA1  = (u32*)(smem + 32768);      // [8][32]
    u64*  sA2  = (u64*)(smem + 34432);      // [24][32]
    // post-L3 aliases:
    u64*  sW4  = (u64*)smem;                // [1536]
    u64*  sWf  = (u64*)(smem + 12288);      // [320]
    u64*  sFeat = (u64*)(smem + 26880);     // [4][32]
    short* sT4 = (short*)(smem + 27904);    // [128]
    float* sBf = (float*)(smem + 28160);    // [10]
    u32*  sA3u = (u32*)(smem + 28288);      // [24*64]
    u64*  sA3q = (u64*)(smem + 28288);      // [24*32]

    int t = threadIdx.x;
    for (int i = t; i < 1536; i += 256) sB3[i] = b3i8[i];
    {
        u32 b = t & 255;
        u64 e = 0;
#pragma unroll
        for (int j = 0; j < 8; ++j)
            e |= (((b >> j) & 1) ? 0x01ull : 0xFFull) << (8 * j);
        if (t < 256) sLUT[t] = e;
    }
    if (t < 128) sC3[t] = (short)C3g[t];
    if (t < 64) sW2[t] = wt2v[t];
    if (t < 192) sT2[t] = (short)T2g[t];

    int co = t & 31, lane = t & 63;
    float4 wa = s1p[co * 3 + 0];
    float4 wb = s1p[co * 3 + 1];
    float wc = s1p[co * 3 + 2].x;
    float Tt = T1g[co];

    int bh0 = blockIdx.x * RB;
    for (int ch = 0; ch < 3; ++ch) {
        __syncthreads();                       // protect sX/sA1 reuse across chunks
        for (int i = t; i < 8 * 140; i += 256) {
            int r = i / 140, c = i % 140;
            float v = 0.f;
            if (c >= 4 && c < 132) v = x[(size_t)(bh0 + ch * 8 + r) * 128 + (c - 4)];
            sX[r * 140 + c] = v;
        }
        __syncthreads();
        // ----- L1 (verified body) -----
        {
            int rr = t >> 5;
            const float* xr = &sX[rr * 140];
            float4 A0 = *(const float4*)&xr[0];
            float4 A1 = *(const float4*)&xr[4];
            float4 A2 = *(const float4*)&xr[8];
            u32 myword = 0;
#pragma unroll
            for (int wp = 0; wp < 32; ++wp) {
                float sum0 = 0.f, sum1 = 0.f;
                sum0 = fmaf(wa.x, A0.x, sum0);  sum1 = fmaf(wa.x, A0.z, sum1);
                sum0 = fmaf(wa.y, A0.y, sum0);  sum1 = fmaf(wa.y, A0.w, sum1);
                sum0 = fmaf(wa.z, A0.z, sum0);  sum1 = fmaf(wa.z, A1.x, sum1);
                sum0 = fmaf(wa.w, A0.w, sum0);  sum1 = fmaf(wa.w, A1.y, sum1);
                sum0 = fmaf(wb.x, A1.x, sum0);  sum1 = fmaf(wb.x, A1.z, sum1);
                sum0 = fmaf(wb.y, A1.y, sum0);  sum1 = fmaf(wb.y, A1.w, sum1);
                sum0 = fmaf(wb.z, A1.z, sum0);  sum1 = fmaf(wb.z, A2.x, sum1);
                sum0 = fmaf(wb.w, A1.w, sum0);  sum1 = fmaf(wb.w, A2.y, sum1);
                sum0 = fmaf(wc,   A2.x, sum0);  sum1 = fmaf(wc,   A2.z, sum1);
                bool pred = fmaxf(sum0, sum1) >= Tt;
                u64 mk = __ballot(pred);
                u32 hw = (lane < 32) ? (u32)mk : (u32)(mk >> 32);
                if ((lane & 31) == wp) myword = hw;
                A0 = A1; A1 = A2;
                A2 = *(const float4*)&xr[4 * wp + 12];   // wp=31 -> [136..139], in-bounds
            }
            sA1[(((t >> 6) << 1) + (lane >> 5)) * 32 + (lane & 31)] = myword;
        }
        __syncthreads();
        // ----- L2 (verified body) -----
        {
            int r = t >> 5, wp = t & 31;
            u32 am = sA1[r * 32 + wp];
            u32 al = (wp > 0) ? sA1[r * 32 + wp - 1] : 0u;
            u32 ar = (wp < 31) ? sA1[r * 32 + wp + 1] : 0u;
            const short* Tp = &sT2[(wp == 0) ? 64 : ((wp == 31) ? 128 : 0)];
            u64 word2 = 0;
#pragma unroll
            for (int c = 0; c < 64; ++c) {
                uint4 w2v = sW2[c];
                int p = __popc(al ^ w2v.x) + __popc(am ^ w2v.y) + __popc(ar ^ w2v.z);
                word2 |= (u64)(p <= (int)Tp[c]) << c;
            }
            sA2[(ch * 8 + r) * 32 + wp] = word2;
        }
    }
    __syncthreads();

    // ----- L3 (verified MFMA body; output to LDS sA3) -----
    int wq = t >> 6, m = lane & 31, half = lane >> 5;
    const int prTab[8] = {0, 1, 4, 5, 8, 9, 12, 13};
    for (int r6 = 0; r6 < 6; ++r6) {
        int row = wq * 6 + r6;
        u64 aw = sA2[row * 32 + m];
        u64 wm1 = (m > 0) ? sA2[row * 32 + m - 1] : 0ull;
        u64 wp1 = (m < 31) ? sA2[row * 32 + m + 1] : 0ull;

        v4i A[6];
#pragma unroll
        for (int kk = 0; kk < 6; ++kk) {
            const int kw = kk >> 1;
            u64 word = (kw == 0) ? wm1 : ((kw == 1) ? aw : wp1);
            bool valid = !((kw == 0 && m == 0) || (kw == 2 && m == 31));
            int ci0 = ((kk & 1) << 5) + (half << 4);
            u32 bits = (u32)(word >> ci0) & 0xFFFFu;
            u64 lo = sLUT[bits & 0xFF];
            u64 hi = sLUT[bits >> 8];
            if (!valid) { lo = 0; hi = 0; }
            union { u64 q[2]; v4i v; } u;
            u.q[0] = lo; u.q[1] = hi;
            A[kk] = u.v;
        }
        u32 outv = 0;
#pragma unroll
        for (int nt = 0; nt < 4; ++nt) {
            v16i acc;
#pragma unroll
            for (int i = 0; i < 16; ++i) acc[i] = 0;
#pragma unroll
            for (int kk = 0; kk < 6; ++kk) {
                int q = kk * 2 + half;
                union { uint4 u4; v4i v; } bu;
                bu.u4 = sB3[q * 128 + nt * 32 + m];
                acc = __builtin_amdgcn_mfma_i32_32x32x32_i8(A[kk], bu.v, acc, 0, 0, 0);
            }
            int tc = (int)sC3[nt * 32 + m];
#pragma unroll
            for (int rp = 0; rp < 8; ++rp) {
                bool c = (acc[2 * rp] >= tc) || (acc[2 * rp + 1] >= tc);
                u64 mk = __ballot(c);
                int LA = (nt << 4) | prTab[rp];
                int LB = LA + 2;
                outv = (lane == LA) ? (u32)mk : outv;
                outv = (lane == LB) ? (u32)(mk >> 32) : outv;
            }
        }
        sA3u[row * 64 + ((lane & 15) << 2) + (lane >> 4)] = outv;
    }
    __syncthreads();     // all L3 sB3/sW2/sT2 reads done; sA3 complete

    // ----- stage L4/FC weights into dead regions -----
    for (int i = t; i < 1536; i += 256) sW4[i] = wt4[i];
    for (int i = t; i < 320; i += 256) sWf[i] = wtf[i];
    if (t < 128) sT4[t] = (short)T4g[t];
    if (t < 10) sBf[t] = bfg[t];
    __syncthreads();

    // ----- L4: wave = 1 local batch; lane = (cg = lane>>4 co-group, w = lane&15) -----
    {
        int bb = t >> 6;            // local batch 0..3
        int w = lane & 15;
        int cg = lane >> 4;         // co-group 0..3 (32 co each)
        u64 av[12];
#pragma unroll
        for (int h = 0; h < 6; ++h) {
            av[h * 2 + 0] = sA3q[(bb * 6 + h) * 32 + w * 2 + 0];
            av[h * 2 + 1] = sA3q[(bb * 6 + h) * 32 + w * 2 + 1];
        }
        u64 acc = 0;
#pragma unroll 4
        for (int c = 0; c < 32; ++c) {
            int cc = cg * 32 + c;
            const u64* wr = &sW4[cc * 12];
            int p = 0;
#pragma unroll
            for (int q = 0; q < 12; ++q) p += __popcll(av[q] ^ wr[q]);
            u64 mk = __ballot(p <= (int)sT4[cc]);
            u64 field = (mk >> (cg * 16)) & 0xFFFFull;   // this co-group's 16 w-bits
            acc |= field << ((c & 3) << 4);
            if ((c & 3) == 3) {
                if (w == (c >> 2)) sFeat[bb * 32 + cg * 8 + (c >> 2)] = acc;
                acc = 0;
            }
        }
    }
    __syncthreads();
    // ----- FC: 4 batches x 10 outputs -----
    if (t < 40) {
        int fb = t / 10, o = t % 10;
        int p = 0;
#pragma unroll
        for (int wi = 0; wi < 32; ++wi) p += __popcll(sFeat[fb * 32 + wi] ^ sWf[o * 32 + wi]);
        out[(size_t)(blockIdx.x * 4 + fb) * 10 + o] = __fadd_rn((float)(2048 - 2 * p), sBf[o]);
    }
}

// ---------------- launch ----------------
extern "C" void kernel_launch(void* const* d_in, const int* in_sizes, int n_in,
                              void* d_out, int out_size, void* d_ws, size_t ws_size,
                              hipStream_t stream) {
    const float* x  = (const float*)d_in[0];
    const float* w1 = (const float*)d_in[1];  const float* b1 = (const float*)d_in[2];
    const float* w2 = (const float*)d_in[3];  const float* b2 = (const float*)d_in[4];
    const float* w3 = (const float*)d_in[5];  const float* b3 = (const float*)d_in[6];
    const float* w4 = (const float*)d_in[7];  const float* b4 = (const float*)d_in[8];
    const float* g1 = (const float*)d_in[9];  const float* be1 = (const float*)d_in[10];
    const float* m1 = (const float*)d_in[11]; const float* v1 = (const float*)d_in[12];
    const float* g2 = (const float*)d_in[13]; const float* be2 = (const float*)d_in[14];
    const float* m2 = (const float*)d_in[15]; const float* v2 = (const float*)d_in[16];
    const float* g3 = (const float*)d_in[17]; const float* be3 = (const float*)d_in[18];
    const float* m3 = (const float*)d_in[19]; const float* v3 = (const float*)d_in[20];
    const float* g4 = (const float*)d_in[21]; const float* be4 = (const float*)d_in[22];
    const float* m4 = (const float*)d_in[23]; const float* v4 = (const float*)d_in[24];
    const float* wf = (const float*)d_in[25]; const float* bf = (const float*)d_in[26];
    float* out = (float*)d_out;

    char* ws = (char*)d_ws;
    const size_t S = 0;
    uint4* b3i8 = (uint4*)(ws + S + 0);       // 24576 B
    u64*  wt4  = (u64*) (ws + S + 24576);     // 12288 B
    u64*  wtf  = (u64*) (ws + S + 36864);     // 2560 B
    u32*  wt2w = (u32*) (ws + S + 39424);     // 1024 B
    float* s1f = (float*)(ws + S + 40448);    // 1536 B
    float* T1  = (float*)(ws + S + 41984);    // 128 B
    int*  T2   = (int*)  (ws + S + 42112);    // 768 B
    int*  C3   = (int*)  (ws + S + 42880);    // 512 B
    int*  T4   = (int*)  (ws + S + 43392);    // 512 B

    prep_all<<<18, 256, 0, stream>>>(w1, b1, w2, b2, w3, b3, w4, b4, wf,
                                     g1, be1, m1, v1, g2, be2, m2, v2,
                                     g3, be3, m3, v3, g4, be4, m4, v4,
                                     s1f, T1, wt2w, T2, b3i8, C3, wt4, T4, wtf);

    mega_kernel<<<(BATCH * 6) / RB, 256, 0, stream>>>(
        x, (const float4*)s1f, T1, (const uint4*)wt2w, T2, b3i8, C3,
        wt4, T4, wtf, bf, out);
}